// Round 5
// baseline (1214.355 us; speedup 1.0000x reference)
//
#include <hip/hip_runtime.h>
#include <hip/hip_bf16.h>
#include <math.h>

#define Ldim 16
#define BATCH 8
#define HWdim 1024

typedef __attribute__((ext_vector_type(8))) short s8v;
typedef __attribute__((ext_vector_type(4))) short s4v;
typedef __attribute__((ext_vector_type(2))) short s2v;
typedef __attribute__((ext_vector_type(4))) float f32x4;
typedef __attribute__((ext_vector_type(2))) float f32x2;

typedef const __attribute__((address_space(1))) void gas_void;
typedef __attribute__((address_space(3))) void las_void;

__device__ __forceinline__ short f2bf(float f) {
    __hip_bfloat16 h = __float2bfloat16(f);
    return __builtin_bit_cast(short, h);
}
__device__ __forceinline__ float bf2f(short s) {
    __hip_bfloat16 h = __builtin_bit_cast(__hip_bfloat16, s);
    return __bfloat162float(h);
}

// ---------------- prep: A_bar + bf16 weight repack ----------------
// X channel layout: ch = 2p+ri. Wb[t][cout=2p+ri][u] = step[p]*B_ri[p][u][t][ri]
// Wc[t][u][k=2p+ri] = (ri? -2 : 2) * C_ri[u][p][t][ri]
__global__ __launch_bounds__(256)
void prep_kernel(const float* __restrict__ Lre, const float* __restrict__ Lim,
                 const float* __restrict__ B_ri, const float* __restrict__ C_ri,
                 const float* __restrict__ log_step, short* __restrict__ Wb,
                 short* __restrict__ Wc, float* __restrict__ Abar) {
    int tid = blockIdx.x * 256 + threadIdx.x;
    if (tid < 256) {
        float st = expf(log_step[tid]);
        Abar[tid] = fminf(Lre[tid], -1e-4f) * st;
        Abar[256 + tid] = Lim[tid] * st;
    }
    const int total = 9 * 512 * 128;
    for (int i = tid; i < total; i += gridDim.x * 256) {
        {   // Wb: i = (t*512 + cout)*128 + u
            int u = i & 127;
            int tc = i >> 7;
            int cout = tc & 511;
            int t = tc >> 9;
            int p = cout >> 1, ri = cout & 1;
            float val = B_ri[(((size_t)p * 128 + u) * 9 + t) * 2 + ri] * expf(log_step[p]);
            Wb[i] = f2bf(val);
        }
        {   // Wc: i = (t*128 + u)*512 + k
            int k = i & 511;
            int tu = i >> 9;
            int uu = tu & 127;
            int t = tu >> 7;
            int p = k >> 1, ri = k & 1;
            float val = C_ri[(((size_t)uu * 256 + p) * 9 + t) * 2 + ri];
            val = ri ? -2.f * val : 2.f * val;
            Wc[i] = f2bf(val);
        }
    }
}

// ---------------- u -> bf16 once ----------------
__global__ __launch_bounds__(256)
void ubf_kernel(const float* __restrict__ u, short* __restrict__ Ubf) {
    size_t t8 = ((size_t)blockIdx.x * 256 + threadIdx.x) * 8;
    f32x4 v0 = *(const f32x4*)(u + t8);
    f32x4 v1 = *(const f32x4*)(u + t8 + 4);
    s8v o;
#pragma unroll
    for (int j = 0; j < 4; ++j) { o[j] = f2bf(v0[j]); o[4 + j] = f2bf(v1[j]); }
    *(s8v*)(Ubf + t8) = o;
}

// ---------------- MFMA implicit-GEMM 3x3 SAME conv ----------------
// grid (8 rowgroups, COUT/128, 128 imgs), block 256 = 4 waves (2M x 2N).
// Tile: 128 px (4 rows x 32) x 128 couts. Single LDS buffer: 6x34 halo patch,
// 64 ch per round, 16B-chunk XOR swizzle (c ^ p&7) folded into the per-lane
// global address for the DMA path. m97 2-barrier K-loop with EXPLICIT
// s_waitcnt vmcnt(0) before the pre-compute barrier (global_load_lds drain is
// not guaranteed by __syncthreads alone -- R4's replay race).
template <int CIN, int COUT, bool ABF16, bool RMW>
__global__ __launch_bounds__(256, 4)
void conv_mfma(const void* __restrict__ inbuf, const short* __restrict__ Wt,
               short* __restrict__ outbuf) {
    constexpr int NCH = CIN / 64;
    __shared__ short lds[13312];  // 26,624 B -> 6 blocks/CU LDS budget

    const int tid = threadIdx.x;
    const int lane = tid & 63;
    const int wv = tid >> 6;
    const int waveM = wv & 1, waveN = wv >> 1;
    const int lm = lane & 15, quad = lane >> 4;
    const int h0 = blockIdx.x * 4;
    const int cgp = blockIdx.y;
    const int img = blockIdx.z;

    const short* inb16 = (const short*)inbuf;
    const float* inb32 = (const float*)inbuf;

    f32x4 acc[4][4];
#pragma unroll
    for (int mt = 0; mt < 4; ++mt)
#pragma unroll
        for (int nt = 0; nt < 4; ++nt)
            acc[mt][nt] = (f32x4){0.f, 0.f, 0.f, 0.f};

    // zero once: halo slots are never DMA/store targets in any round
    for (int i = tid; i < 1664; i += 256)
        *(s8v*)&lds[i * 8] = (s8v){0, 0, 0, 0, 0, 0, 0, 0};
    __syncthreads();

#pragma unroll 1
    for (int ch = 0; ch < NCH; ++ch) {
        if (ch) __syncthreads();  // all waves done reading previous round
        if (ABF16) {
            // async DMA: wave wv stages chunk-blocks k (64 chunks each);
            // lane writes lds[k*512 + lane*8] <- global chunk q=k*64+lane,
            // channel cs = (q&7)^(p&7) (swizzle folded into global addr)
            for (int k = wv; k < 26; k += 4) {
                int q = k * 64 + lane;
                int p = q >> 3;
                int cs = (q & 7) ^ (p & 7);
                int sr = p / 34;
                int w34 = p - sr * 34;
                int habs = h0 - 1 + sr, wabs = w34 - 1;
                if (q < 1632 && (unsigned)habs < 32u && (unsigned)wabs < 32u) {
                    const short* g = inb16 + ((size_t)img * HWdim + habs * 32 + wabs) * CIN +
                                     ch * 64 + cs * 8;
                    __builtin_amdgcn_global_load_lds((gas_void*)g, (las_void*)&lds[k * 512],
                                                     16, 0, 0);
                }
            }
            __builtin_amdgcn_s_waitcnt(0x0F70);  // vmcnt(0): DMA drained
        } else {
            // sync staging from fp32 source (convert in regs, ds_write)
            for (int idx = tid; idx < 1632; idx += 256) {
                int cgi = idx & 7;
                int pos = idx >> 3;
                int sr = pos / 34;
                int w34 = pos - sr * 34;
                int habs = h0 - 1 + sr, wabs = w34 - 1;
                if ((unsigned)habs < 32u && (unsigned)wabs < 32u) {
                    const float* src = inb32 + ((size_t)img * HWdim + habs * 32 + wabs) * CIN +
                                       ch * 64 + cgi * 8;
                    f32x4 a0 = *(const f32x4*)src;
                    f32x4 a1 = *(const f32x4*)(src + 4);
                    s8v v;
#pragma unroll
                    for (int j = 0; j < 4; ++j) { v[j] = f2bf(a0[j]); v[4 + j] = f2bf(a1[j]); }
                    *(s8v*)&lds[((pos << 3) + (cgi ^ (pos & 7))) << 3] = v;
                }
            }
        }
        __syncthreads();

#pragma unroll
        for (int kh = 0; kh < 3; ++kh)
#pragma unroll
            for (int kw = 0; kw < 3; ++kw) {
                int t = kh * 3 + kw;
                const short* wbase = Wt +
                    ((size_t)t * COUT + cgp * 128 + waveN * 64 + lm) * CIN + ch * 64 + quad * 8;
#pragma unroll
                for (int ks = 0; ks < 2; ++ks) {
                    s8v a[4], bfr[4];
#pragma unroll
                    for (int nt = 0; nt < 4; ++nt)
                        bfr[nt] = *(const s8v*)&wbase[(size_t)(nt * 16) * CIN + ks * 32];
#pragma unroll
                    for (int mt = 0; mt < 4; ++mt) {
                        int p = (waveM * 2 + (mt >> 1) + kh) * 34 + (mt & 1) * 16 + lm + kw;
                        int c = ks * 4 + quad;
                        a[mt] = *(const s8v*)&lds[(((p << 3) + (c ^ (p & 7))) << 3)];
                    }
#pragma unroll
                    for (int mt = 0; mt < 4; ++mt)
#pragma unroll
                        for (int nt = 0; nt < 4; ++nt)
                            acc[mt][nt] = __builtin_amdgcn_mfma_f32_16x16x32_bf16(
                                a[mt], bfr[nt], acc[mt][nt], 0, 0, 0);
                }
            }
    }

    // epilogue: C/D row(m)=quad*4+reg (pixel), col(n)=lm (cout)
#pragma unroll
    for (int mt = 0; mt < 4; ++mt) {
#pragma unroll
        for (int reg = 0; reg < 4; ++reg) {
            int mm = waveM * 64 + mt * 16 + quad * 4 + reg;
            int r = mm >> 5, w = mm & 31;
            size_t rowbase = ((size_t)img * HWdim + (h0 + r) * 32 + w) * COUT +
                             cgp * 128 + waveN * 64 + lm;
#pragma unroll
            for (int nt = 0; nt < 4; ++nt) {
                size_t oidx = rowbase + nt * 16;
                float val = acc[mt][nt][reg];
                if (RMW) val += bf2f(outbuf[oidx]);
                outbuf[oidx] = f2bf(val);
            }
        }
    }
}

// ---------------- sequential diagonal scan, in-place on X, fp32 state ----------------
__global__ __launch_bounds__(256)
void scan_kernel(const float* __restrict__ x0, const float* __restrict__ Abar,
                 short* __restrict__ X, float* __restrict__ out_xlast) {
    int p = threadIdx.x;
    int hw = blockIdx.x;
    int b = blockIdx.y;
    float Ar = Abar[p], Ai = Abar[256 + p];
    float xr = x0[((size_t)b * HWdim + hw) * 256 + p];
    float xi = 0.f;
    for (int l = 0; l < Ldim; ++l) {
        size_t base = ((size_t)(l * 8 + b) * HWdim + hw) * 512 + p * 2;
        s2v v = *(s2v*)&X[base];
        float br = bf2f(v[0]), bim = bf2f(v[1]);
        float nr = Ar * xr - Ai * xi + br;
        float ni = Ar * xi + Ai * xr + bim;
        xr = nr; xi = ni;
        v[0] = f2bf(xr); v[1] = f2bf(xi);
        *(s2v*)&X[base] = v;
    }
    f32x2 o2 = {xr, xi};
    *(f32x2*)&out_xlast[(((size_t)b * HWdim + hw) * 256 + p) * 2] = o2;
}

// ---------------- depthwise D conv -> ys (bf16), 4 ch/thread ----------------
template <bool UBF>
__global__ __launch_bounds__(256)
void du_kernel(const void* __restrict__ uin, const float* __restrict__ Dk,
               short* __restrict__ ys) {
    int tid = blockIdx.x * 256 + threadIdx.x;  // 128 imgs * 1024 px * 32 c4
    int c4 = tid & 31;
    int hw = (tid >> 5) & 1023;
    int img = tid >> 15;
    int h = hw >> 5, w = hw & 31;
    size_t fbase = (size_t)img * HWdim * 128;
    float s0 = 0.f, s1 = 0.f, s2 = 0.f, s3 = 0.f;
#pragma unroll
    for (int kh = 0; kh < 3; ++kh)
#pragma unroll
        for (int kw = 0; kw < 3; ++kw) {
            int hh = h + kh - 1, wc = w + kw - 1;
            if ((unsigned)hh < 32u && (unsigned)wc < 32u) {
                f32x4 d = *(const f32x4*)&Dk[(kh * 3 + kw) * 128 + c4 * 4];
                size_t off = fbase + ((size_t)hh * 32 + wc) * 128 + c4 * 4;
                if (UBF) {
                    s4v v = *(const s4v*)((const short*)uin + off);
                    s0 += bf2f(v[0]) * d[0]; s1 += bf2f(v[1]) * d[1];
                    s2 += bf2f(v[2]) * d[2]; s3 += bf2f(v[3]) * d[3];
                } else {
                    f32x4 v = *(const f32x4*)((const float*)uin + off);
                    s0 += v[0] * d[0]; s1 += v[1] * d[1];
                    s2 += v[2] * d[2]; s3 += v[3] * d[3];
                }
            }
        }
    s4v o = {f2bf(s0), f2bf(s1), f2bf(s2), f2bf(s3)};
    *(s4v*)&ys[(size_t)tid * 4] = o;
}

// ---------------- group norm stats: one block per img, coalesced ----------------
__global__ __launch_bounds__(256)
void gnstats_kernel(const short* __restrict__ ys, float* __restrict__ stats) {
    int img = blockIdx.x;
    int tid = threadIdx.x;
    const short* base = ys + (size_t)img * 131072;
    float s0 = 0.f, q0 = 0.f, s1 = 0.f, q1 = 0.f;
    for (int i = tid; i < 16384; i += 256) {  // octet = i&15 == tid&15 (stride 256)
        s8v v = *(const s8v*)&base[i * 8];
#pragma unroll
        for (int j = 0; j < 4; ++j) { float f = bf2f(v[j]); s0 += f; q0 += f * f; }
#pragma unroll
        for (int j = 4; j < 8; ++j) { float f = bf2f(v[j]); s1 += f; q1 += f * f; }
    }
    __shared__ float red[256][4];
    red[tid][0] = s0; red[tid][1] = q0; red[tid][2] = s1; red[tid][3] = q1;
    __syncthreads();
    if (tid < 32) {  // group g = tid; octet o = g>>1, half h = g&1
        int o = tid >> 1, h = tid & 1;
        float S = 0.f, Q = 0.f;
#pragma unroll
        for (int j = 0; j < 16; ++j) {
            S += red[o + 16 * j][h * 2];
            Q += red[o + 16 * j][h * 2 + 1];
        }
        const float inv = 1.f / 4096.f;
        float mean = S * inv;
        float var = Q * inv - mean * mean;
        stats[(img * 32 + tid) * 2 + 0] = mean;
        stats[(img * 32 + tid) * 2 + 1] = var;
    }
}

// ---------------- apply GN + gelu(tanh), 4 ch/thread ----------------
__global__ __launch_bounds__(256)
void gnapply_kernel(const short* __restrict__ ys, const float* __restrict__ stats,
                    const float* __restrict__ scale, const float* __restrict__ bias,
                    float* __restrict__ out_ys) {
    int tid = blockIdx.x * 256 + threadIdx.x;
    int c4 = tid & 31;
    int img = tid >> 15;
    float mean = stats[(img * 32 + c4) * 2 + 0];
    float var = stats[(img * 32 + c4) * 2 + 1];
    float rstd = rsqrtf(var + 1e-5f);
    s4v v = *(const s4v*)&ys[(size_t)tid * 4];
    f32x4 sc = *(const f32x4*)&scale[c4 * 4];
    f32x4 bs = *(const f32x4*)&bias[c4 * 4];
    f32x4 o;
    const float kAlpha = 0.7978845608028654f;
#pragma unroll
    for (int j = 0; j < 4; ++j) {
        float y = (bf2f(v[j]) - mean) * rstd * sc[j] + bs[j];
        float t = kAlpha * (y + 0.044715f * y * y * y);
        o[j] = 0.5f * y * (1.f + tanhf(t));
    }
    *(f32x4*)&out_ys[(size_t)tid * 4] = o;
}

extern "C" void kernel_launch(void* const* d_in, const int* in_sizes, int n_in,
                              void* d_out, int out_size, void* d_ws, size_t ws_size,
                              hipStream_t stream) {
    const float* useq = (const float*)d_in[0];
    const float* x0 = (const float*)d_in[1];
    const float* Lre = (const float*)d_in[2];
    const float* Lim = (const float*)d_in[3];
    const float* B_ri = (const float*)d_in[4];
    const float* C_ri = (const float*)d_in[5];
    const float* log_step = (const float*)d_in[6];
    const float* Dk = (const float*)d_in[7];
    const float* gsc = (const float*)d_in[8];
    const float* gbi = (const float*)d_in[9];
    float* out = (float*)d_out;

    const size_t WB = 1179648;
    char* wsb = (char*)d_ws;
    short* Wb = (short*)(wsb);
    short* Wc = (short*)(wsb + WB);
    float* Abar = (float*)(wsb + 2 * WB);
    float* stats = (float*)(wsb + 2 * WB + 2048);
    size_t offX = 2 * WB + 2048 + 32768;
    short* X = (short*)(wsb + offX);
    size_t offYS = offX + 134217728;
    short* YS = (short*)(wsb + offYS);
    size_t offU = offYS + 33554432;
    short* Ubf = (short*)(wsb + offU);
    bool ubf = ws_size >= offU + 33554432;

    prep_kernel<<<2304, 256, 0, stream>>>(Lre, Lim, B_ri, C_ri, log_step, Wb, Wc, Abar);

    if (ubf) {
        ubf_kernel<<<8192, 256, 0, stream>>>(useq, Ubf);
        conv_mfma<128, 512, true, false><<<dim3(8, 4, 128), 256, 0, stream>>>(Ubf, Wb, X);
    } else {
        conv_mfma<128, 512, false, false><<<dim3(8, 4, 128), 256, 0, stream>>>(useq, Wb, X);
    }
    scan_kernel<<<dim3(HWdim, 8), 256, 0, stream>>>(x0, Abar, X, out);
    if (ubf)
        du_kernel<true><<<16384, 256, 0, stream>>>(Ubf, Dk, YS);
    else
        du_kernel<false><<<16384, 256, 0, stream>>>(useq, Dk, YS);
    conv_mfma<512, 128, true, true><<<dim3(8, 1, 128), 256, 0, stream>>>(X, Wc, YS);
    gnstats_kernel<<<128, 256, 0, stream>>>(YS, stats);
    gnapply_kernel<<<16384, 256, 0, stream>>>(YS, stats, gsc, gbi, out + 4194304);
}